// Round 2
// baseline (162.412 us; speedup 1.0000x reference)
//
#include <hip/hip_runtime.h>

// Problem: B=32, T=2048, E=128, all fp32.
// Key identity: S never materialized.
//   sx1[b] = sum_t x1[b,t,:], sx2[b] = sum_t x2[b,t,:]
//   w1[t] = x1[b,t].sx2[b];  c1 = (1/T) sum_t w1[t]*x2[b,t,:]
//   w2[t] = x2[b,t].sx1[b];  c2 = (1/T) sum_t w2[t]*x1[b,t,:]
//   et1[t] = c1.U1[:,t] + x1[b,t].W1 + b1[t]; softmax; o1 = sum_t at1[t]*x1[b,t,:]
// Output: concat([o1,o2],axis=1) -> (B, 2E)

#define B_ 32
#define T_ 2048
#define E_ 128
#define INV_T (1.0f/2048.0f)

// ws layout (floats):
//   0                : sx1  B*E   (4096)   zeroed
//   4096             : sx2  B*E            zeroed
//   8192             : c1   B*E            zeroed
//   12288            : c2   B*E            zeroed
//   16384            : et1  B*T   (65536)  written
//   81920            : et2  B*T            written
//   147456           : m1[B] l1[B] m2[B] l2[B]  written
#define WS_SX1 0
#define WS_SX2 (B_*E_)
#define WS_C1  (2*B_*E_)
#define WS_C2  (3*B_*E_)
#define WS_ET1 (4*B_*E_)
#define WS_ET2 (4*B_*E_ + B_*T_)
#define WS_SM  (4*B_*E_ + 2*B_*T_)

// ---------------- P1: column sums over t ----------------
__global__ void k1_colsum(const float* __restrict__ x1, const float* __restrict__ x2,
                          float* __restrict__ ws) {
    int b = blockIdx.x, chunk = blockIdx.y;
    int tid = threadIdx.x;
    int e   = tid & (E_ - 1);
    int sel = tid >> 7;                    // 0 -> x1, 1 -> x2
    const float* x = sel ? x2 : x1;
    float* sx = ws + (sel ? WS_SX2 : WS_SX1);
    int t0 = chunk * 128;
    const float* p = x + ((size_t)b * T_ + t0) * E_ + e;
    float acc = 0.f;
    #pragma unroll 8
    for (int r = 0; r < 128; ++r) acc += p[(size_t)r * E_];
    atomicAdd(&sx[b * E_ + e], acc);
}

// ---------------- P2: w, c accumulation, x.W logit term ----------------
__global__ void k2_wc(const float* __restrict__ x1, const float* __restrict__ x2,
                      const float* __restrict__ W1, const float* __restrict__ b1,
                      const float* __restrict__ W2, const float* __restrict__ b2,
                      float* __restrict__ ws) {
    __shared__ float s_sx1[E_], s_sx2[E_], s_W1[E_], s_W2[E_];
    __shared__ float s_w1[256], s_w2[256];
    int b = blockIdx.x, chunk = blockIdx.y;
    int tid = threadIdx.x;
    float* c1  = ws + WS_C1;
    float* c2  = ws + WS_C2;
    float* et1 = ws + WS_ET1;
    float* et2 = ws + WS_ET2;
    if (tid < E_) {
        s_sx1[tid] = ws[WS_SX1 + b * E_ + tid];
        s_sx2[tid] = ws[WS_SX2 + b * E_ + tid];
        s_W1[tid]  = W1[tid];
        s_W2[tid]  = W2[tid];
    }
    __syncthreads();

    int t0  = chunk * 256;
    int row = t0 + tid;
    const float4* r1   = (const float4*)(x1 + ((size_t)b * T_ + row) * E_);
    const float4* r2   = (const float4*)(x2 + ((size_t)b * T_ + row) * E_);
    const float4* ssx1 = (const float4*)s_sx1;
    const float4* ssx2 = (const float4*)s_sx2;
    const float4* sW1v = (const float4*)s_W1;
    const float4* sW2v = (const float4*)s_W2;
    float w1 = 0.f, xw1 = 0.f, w2 = 0.f, xw2 = 0.f;
    #pragma unroll 8
    for (int i = 0; i < E_ / 4; ++i) {
        float4 a = r1[i], s = ssx2[i], wv = sW1v[i];
        w1  += a.x * s.x  + a.y * s.y  + a.z * s.z  + a.w * s.w;
        xw1 += a.x * wv.x + a.y * wv.y + a.z * wv.z + a.w * wv.w;
        float4 c = r2[i], u = ssx1[i], vv = sW2v[i];
        w2  += c.x * u.x  + c.y * u.y  + c.z * u.z  + c.w * u.w;
        xw2 += c.x * vv.x + c.y * vv.y + c.z * vv.z + c.w * vv.w;
    }
    s_w1[tid] = w1;
    s_w2[tid] = w2;
    et1[(size_t)b * T_ + row] = xw1 + b1[row];
    et2[(size_t)b * T_ + row] = xw2 + b2[row];
    __syncthreads();

    int e   = tid & (E_ - 1);
    int sel = tid >> 7;
    float acc = 0.f;
    if (sel == 0) {
        const float* p = x2 + ((size_t)b * T_ + t0) * E_ + e;
        #pragma unroll 8
        for (int r = 0; r < 256; ++r) acc += s_w1[r] * p[(size_t)r * E_];
        atomicAdd(&c1[b * E_ + e], acc * INV_T);
    } else {
        const float* p = x1 + ((size_t)b * T_ + t0) * E_ + e;
        #pragma unroll 8
        for (int r = 0; r < 256; ++r) acc += s_w2[r] * p[(size_t)r * E_];
        atomicAdd(&c2[b * E_ + e], acc * INV_T);
    }
}

// ---------------- P3: et += c.U (coalesced over t) ----------------
__global__ void k3_et(const float* __restrict__ U1, const float* __restrict__ U2,
                      float* __restrict__ ws) {
    __shared__ float s_c1[E_], s_c2[E_];
    int b = blockIdx.x, chunk = blockIdx.y;
    int tid = threadIdx.x;
    float* et1 = ws + WS_ET1;
    float* et2 = ws + WS_ET2;
    if (tid < E_) s_c1[tid] = ws[WS_C1 + b * E_ + tid];
    else          s_c2[tid - E_] = ws[WS_C2 + b * E_ + tid - E_];
    __syncthreads();
    int t = chunk * 256 + tid;
    float a1 = et1[(size_t)b * T_ + t];
    float a2 = et2[(size_t)b * T_ + t];
    #pragma unroll 8
    for (int e = 0; e < E_; ++e) {
        a1 += s_c1[e] * U1[(size_t)e * T_ + t];
        a2 += s_c2[e] * U2[(size_t)e * T_ + t];
    }
    et1[(size_t)b * T_ + t] = a1;
    et2[(size_t)b * T_ + t] = a2;
}

// ---------------- P4: per-(b,tensor) softmax max & sum ----------------
__global__ void k4_softmax_reduce(float* __restrict__ ws) {
    __shared__ float red[256];
    int b   = blockIdx.x >> 1;
    int sel = blockIdx.x & 1;
    int tid = threadIdx.x;
    const float* et = ws + (sel ? WS_ET2 : WS_ET1) + (size_t)b * T_;
    float v[8];
    float m = -3.4e38f;
    #pragma unroll
    for (int k = 0; k < 8; ++k) { v[k] = et[tid + k * 256]; m = fmaxf(m, v[k]); }
    red[tid] = m; __syncthreads();
    for (int s = 128; s > 0; s >>= 1) {
        if (tid < s) red[tid] = fmaxf(red[tid], red[tid + s]);
        __syncthreads();
    }
    m = red[0]; __syncthreads();
    float l = 0.f;
    #pragma unroll
    for (int k = 0; k < 8; ++k) l += __expf(v[k] - m);
    red[tid] = l; __syncthreads();
    for (int s = 128; s > 0; s >>= 1) {
        if (tid < s) red[tid] += red[tid + s];
        __syncthreads();
    }
    if (tid == 0) {
        float* sm = ws + WS_SM + sel * 2 * B_;   // [m..., l...]
        sm[b]       = m;
        sm[B_ + b]  = red[0];
    }
}

// ---------------- P5: o = sum_t softmax * x ----------------
__global__ void k5_out(const float* __restrict__ x1, const float* __restrict__ x2,
                       const float* __restrict__ ws, float* __restrict__ out) {
    __shared__ float s_p1[256], s_p2[256];
    int b = blockIdx.x, chunk = blockIdx.y;
    int tid = threadIdx.x;
    const float* et1 = ws + WS_ET1;
    const float* et2 = ws + WS_ET2;
    const float* sm  = ws + WS_SM;
    float m1 = sm[b],          il1 = 1.f / sm[B_ + b];
    float m2 = sm[2 * B_ + b], il2 = 1.f / sm[3 * B_ + b];
    int t0 = chunk * 256;
    s_p1[tid] = __expf(et1[(size_t)b * T_ + t0 + tid] - m1) * il1;
    s_p2[tid] = __expf(et2[(size_t)b * T_ + t0 + tid] - m2) * il2;
    __syncthreads();
    int e   = tid & (E_ - 1);
    int sel = tid >> 7;
    float acc = 0.f;
    if (sel == 0) {
        const float* p = x1 + ((size_t)b * T_ + t0) * E_ + e;
        #pragma unroll 8
        for (int r = 0; r < 256; ++r) acc += s_p1[r] * p[(size_t)r * E_];
        atomicAdd(&out[b * 2 * E_ + e], acc);
    } else {
        const float* p = x2 + ((size_t)b * T_ + t0) * E_ + e;
        #pragma unroll 8
        for (int r = 0; r < 256; ++r) acc += s_p2[r] * p[(size_t)r * E_];
        atomicAdd(&out[b * 2 * E_ + E_ + e], acc);
    }
}

extern "C" void kernel_launch(void* const* d_in, const int* in_sizes, int n_in,
                              void* d_out, int out_size, void* d_ws, size_t ws_size,
                              hipStream_t stream) {
    const float* x1 = (const float*)d_in[0];
    const float* x2 = (const float*)d_in[1];
    const float* W1 = (const float*)d_in[2];
    const float* b1 = (const float*)d_in[3];
    const float* U1 = (const float*)d_in[4];
    const float* W2 = (const float*)d_in[5];
    const float* b2 = (const float*)d_in[6];
    const float* U2 = (const float*)d_in[7];
    float* ws  = (float*)d_ws;
    float* out = (float*)d_out;

    // zero the accumulated regions (sx1,sx2,c1,c2) and the output
    hipMemsetAsync(ws, 0, (size_t)4 * B_ * E_ * sizeof(float), stream);
    hipMemsetAsync(out, 0, (size_t)2 * B_ * E_ * sizeof(float), stream);

    k1_colsum<<<dim3(B_, 16), 256, 0, stream>>>(x1, x2, ws);
    k2_wc<<<dim3(B_, 8), 256, 0, stream>>>(x1, x2, W1, b1, W2, b2, ws);
    k3_et<<<dim3(B_, 8), 256, 0, stream>>>(U1, U2, ws);
    k4_softmax_reduce<<<2 * B_, 256, 0, stream>>>(ws);
    k5_out<<<dim3(B_, 8), 256, 0, stream>>>(x1, x2, ws, out);
}

// Round 4
// 155.133 us; speedup vs baseline: 1.0469x; 1.0469x over previous
//
#include <hip/hip_runtime.h>

// B=32, T=2048, E=128, fp32. S (B,T,T) never materialized:
//   sx1[b]=sum_t x1[b,t,:], sx2[b]=sum_t x2[b,t,:]
//   w1[t]=x1[b,t].sx2[b]; c1=(1/T) sum_t w1[t]*x2[b,t,:]   (sym. for c2)
//   et1[t]=c1.U1[:,t] + x1[b,t].W1 + b1[t]; softmax; o1=sum_t at1[t]*x1[b,t,:]
// 5 plain launches (stream order = phase barrier). No cooperative launch.

#define B_ 32
#define T_ 2048
#define E_ 128
#define EV (E_/4)
#define INV_T (1.0f/2048.0f)

// ws float layout
#define WS_SX1 0
#define WS_SX2 (B_*E_)
#define WS_C1  (2*B_*E_)
#define WS_C2  (3*B_*E_)
#define WS_ET1 (4*B_*E_)                  // later overwritten with probabilities
#define WS_ET2 (4*B_*E_ + B_*T_)
#define WS_ACC_N (4*B_*E_)                // 16384 floats to zero
#define OUT_N (2*B_*E_)                   // 8192 floats to zero

__device__ __forceinline__ float dot4(float4 a, float4 b) {
    return a.x*b.x + a.y*b.y + a.z*b.z + a.w*b.w;
}
__device__ __forceinline__ void fma4(float4& a, float s, const float4 v) {
    a.x += s*v.x; a.y += s*v.y; a.z += s*v.z; a.w += s*v.w;
}
__device__ __forceinline__ void add4(float4& a, const float4 v) {
    a.x += v.x; a.y += v.y; a.z += v.z; a.w += v.w;
}

// ---------------- K0: zero accumulators + out ----------------
__global__ void k0_zero(float* __restrict__ ws, float* __restrict__ out) {
    int i = blockIdx.x * 256 + threadIdx.x;          // grid covers 24576
    if (i < WS_ACC_N) ws[i] = 0.f;
    else               out[i - WS_ACC_N] = 0.f;
}

// ---------------- K1: column sums sx1, sx2 ----------------
__global__ __launch_bounds__(256)
void k1_sx(const float* __restrict__ x1, const float* __restrict__ x2,
           float* __restrict__ ws) {
    __shared__ float4 s_r1[256], s_r2[256];
    const int b = blockIdx.x, ch = blockIdx.y, tid = threadIdx.x;
    const float4* p1 = (const float4*)x1 + ((size_t)b*T_ + ch*64)*EV;
    const float4* p2 = (const float4*)x2 + ((size_t)b*T_ + ch*64)*EV;
    const int rg = tid >> 5, q = tid & 31;
    float4 a1 = {0,0,0,0}, a2 = {0,0,0,0};
    #pragma unroll
    for (int i = 0; i < 8; ++i) {
        int r = i*8 + rg;
        add4(a1, p1[r*EV + q]);
        add4(a2, p2[r*EV + q]);
    }
    s_r1[tid] = a1; s_r2[tid] = a2;
    __syncthreads();
    for (int s = 128; s >= 32; s >>= 1) {
        if (tid < s) { add4(s_r1[tid], s_r1[tid+s]); add4(s_r2[tid], s_r2[tid+s]); }
        __syncthreads();
    }
    if (tid < 32) {
        float4 t1 = s_r1[tid], t2 = s_r2[tid];
        atomicAdd(&ws[WS_SX1 + b*E_ + tid*4+0], t1.x);
        atomicAdd(&ws[WS_SX1 + b*E_ + tid*4+1], t1.y);
        atomicAdd(&ws[WS_SX1 + b*E_ + tid*4+2], t1.z);
        atomicAdd(&ws[WS_SX1 + b*E_ + tid*4+3], t1.w);
        atomicAdd(&ws[WS_SX2 + b*E_ + tid*4+0], t2.x);
        atomicAdd(&ws[WS_SX2 + b*E_ + tid*4+1], t2.y);
        atomicAdd(&ws[WS_SX2 + b*E_ + tid*4+2], t2.z);
        atomicAdd(&ws[WS_SX2 + b*E_ + tid*4+3], t2.w);
    }
}

// ---------------- K2: row weights, x.W logits (et init), c partials ----------------
__global__ __launch_bounds__(256)
void k2_wc(const float* __restrict__ x1, const float* __restrict__ x2,
           const float* __restrict__ W1, const float* __restrict__ b1,
           const float* __restrict__ W2, const float* __restrict__ b2,
           float* __restrict__ ws) {
    __shared__ float4 s_r1[256], s_r2[256];                  // 8 KB reduce scratch
    __shared__ float  s_a[E_], s_b[E_], s_wa[E_], s_wb[E_];  // sx1,sx2,W1,W2
    __shared__ float  s_w1[64], s_w2[64];
    const int b = blockIdx.x, ch = blockIdx.y, tid = threadIdx.x;
    if (tid < E_) {
        s_a[tid]  = ws[WS_SX1 + b*E_ + tid];
        s_b[tid]  = ws[WS_SX2 + b*E_ + tid];
        s_wa[tid] = W1[tid];
        s_wb[tid] = W2[tid];
    }
    __syncthreads();
    const float4* p1 = (const float4*)x1 + ((size_t)b*T_ + ch*64)*EV;
    const float4* p2 = (const float4*)x2 + ((size_t)b*T_ + ch*64)*EV;
    const float4* sx1v = (const float4*)s_a;
    const float4* sx2v = (const float4*)s_b;
    const float4* W1v  = (const float4*)s_wa;
    const float4* W2v  = (const float4*)s_wb;
    const int wv = tid >> 6, l = tid & 63;
    const int rp = l >> 5, q = l & 31;
    const int rowoff = wv*2 + rp;            // == tid>>5

    // load tile once into registers; reused by both phases (same row->lane map)
    float4 v1[8], v2[8];
    #pragma unroll
    for (int i = 0; i < 8; ++i) {
        int r = i*8 + rowoff;
        v1[i] = p1[r*EV + q];
        v2[i] = p2[r*EV + q];
    }

    float* et1 = ws + WS_ET1 + (size_t)b*T_ + ch*64;
    float* et2 = ws + WS_ET2 + (size_t)b*T_ + ch*64;
    #pragma unroll
    for (int i = 0; i < 8; ++i) {
        int r = i*8 + rowoff;
        float pw1 = dot4(v1[i], sx2v[q]);    // x1 . sx2
        float px1 = dot4(v1[i], W1v[q]);     // x1 . W1
        float pw2 = dot4(v2[i], sx1v[q]);    // x2 . sx1
        float px2 = dot4(v2[i], W2v[q]);     // x2 . W2
        #pragma unroll
        for (int m = 1; m <= 16; m <<= 1) {  // reduce across 32 lanes (within half-wave)
            pw1 += __shfl_xor(pw1, m);
            px1 += __shfl_xor(px1, m);
            pw2 += __shfl_xor(pw2, m);
            px2 += __shfl_xor(px2, m);
        }
        if (q == 0) {
            s_w1[r] = pw1; s_w2[r] = pw2;
            int trow = ch*64 + r;
            et1[r] = px1 + b1[trow];
            et2[r] = px2 + b2[trow];
        }
    }
    __syncthreads();

    // c1 += sum_r w1[r]*x2[r,:],  c2 += sum_r w2[r]*x1[r,:]  (tile already in regs)
    float4 a1 = {0,0,0,0}, a2 = {0,0,0,0};
    #pragma unroll
    for (int i = 0; i < 8; ++i) {
        int r = i*8 + rowoff;
        fma4(a1, s_w1[r], v2[i]);
        fma4(a2, s_w2[r], v1[i]);
    }
    s_r1[tid] = a1; s_r2[tid] = a2;
    __syncthreads();
    for (int s = 128; s >= 32; s >>= 1) {
        if (tid < s) { add4(s_r1[tid], s_r1[tid+s]); add4(s_r2[tid], s_r2[tid+s]); }
        __syncthreads();
    }
    if (tid < 32) {
        float4 t1 = s_r1[tid], t2 = s_r2[tid];
        atomicAdd(&ws[WS_C1 + b*E_ + tid*4+0], t1.x * INV_T);
        atomicAdd(&ws[WS_C1 + b*E_ + tid*4+1], t1.y * INV_T);
        atomicAdd(&ws[WS_C1 + b*E_ + tid*4+2], t1.z * INV_T);
        atomicAdd(&ws[WS_C1 + b*E_ + tid*4+3], t1.w * INV_T);
        atomicAdd(&ws[WS_C2 + b*E_ + tid*4+0], t2.x * INV_T);
        atomicAdd(&ws[WS_C2 + b*E_ + tid*4+1], t2.y * INV_T);
        atomicAdd(&ws[WS_C2 + b*E_ + tid*4+2], t2.z * INV_T);
        atomicAdd(&ws[WS_C2 + b*E_ + tid*4+3], t2.w * INV_T);
    }
}

// ---------------- K3: et += c.U, softmax, write probabilities in-place ----------------
__global__ __launch_bounds__(256)
void k3_et_softmax(const float* __restrict__ U1, const float* __restrict__ U2,
                   float* __restrict__ ws) {
    __shared__ float s_c[E_];
    __shared__ float red[256];
    const int b = blockIdx.x, sel = blockIdx.y, tid = threadIdx.x;
    const float* U = sel ? U2 : U1;                       // (E, T) row-major
    const float* cp = ws + (sel ? WS_C2 : WS_C1) + b*E_;
    float4* et4 = (float4*)(ws + (sel ? WS_ET2 : WS_ET1) + (size_t)b*T_);
    if (tid < E_) s_c[tid] = cp[tid];
    __syncthreads();
    const float4* U4 = (const float4*)U;                  // E x (T/4)
    float4 acc0 = et4[tid];                               // et init (x.W + b)
    float4 acc1 = et4[tid + 256];
    #pragma unroll 4
    for (int e = 0; e < E_; ++e) {
        float ce = s_c[e];
        fma4(acc0, ce, U4[(size_t)e*(T_/4) + tid]);
        fma4(acc1, ce, U4[(size_t)e*(T_/4) + tid + 256]);
    }
    // block max
    float m = fmaxf(fmaxf(fmaxf(acc0.x, acc0.y), fmaxf(acc0.z, acc0.w)),
                    fmaxf(fmaxf(acc1.x, acc1.y), fmaxf(acc1.z, acc1.w)));
    red[tid] = m; __syncthreads();
    for (int s = 128; s > 0; s >>= 1) {
        if (tid < s) red[tid] = fmaxf(red[tid], red[tid+s]);
        __syncthreads();
    }
    m = red[0]; __syncthreads();
    // exp + block sum
    float4 e0, e1;
    e0.x = __expf(acc0.x - m); e0.y = __expf(acc0.y - m);
    e0.z = __expf(acc0.z - m); e0.w = __expf(acc0.w - m);
    e1.x = __expf(acc1.x - m); e1.y = __expf(acc1.y - m);
    e1.z = __expf(acc1.z - m); e1.w = __expf(acc1.w - m);
    float lsum = e0.x + e0.y + e0.z + e0.w + e1.x + e1.y + e1.z + e1.w;
    red[tid] = lsum; __syncthreads();
    for (int s = 128; s > 0; s >>= 1) {
        if (tid < s) red[tid] += red[tid+s];
        __syncthreads();
    }
    float il = 1.f / red[0];
    e0.x *= il; e0.y *= il; e0.z *= il; e0.w *= il;
    e1.x *= il; e1.y *= il; e1.z *= il; e1.w *= il;
    et4[tid]       = e0;                                  // et now holds at[t]
    et4[tid + 256] = e1;
}

// ---------------- K5: o = sum_t at[t]*x[t,:] ----------------
__global__ __launch_bounds__(256)
void k5_out(const float* __restrict__ x1, const float* __restrict__ x2,
            const float* __restrict__ ws, float* __restrict__ out) {
    __shared__ float4 s_r1[256], s_r2[256];
    __shared__ float s_p1[64], s_p2[64];
    const int b = blockIdx.x, ch = blockIdx.y, tid = threadIdx.x;
    const float* pr1 = ws + WS_ET1 + (size_t)b*T_ + ch*64;
    const float* pr2 = ws + WS_ET2 + (size_t)b*T_ + ch*64;
    if (tid < 64)        s_p1[tid] = pr1[tid];
    else if (tid < 128)  s_p2[tid - 64] = pr2[tid - 64];
    __syncthreads();
    const float4* p1 = (const float4*)x1 + ((size_t)b*T_ + ch*64)*EV;
    const float4* p2 = (const float4*)x2 + ((size_t)b*T_ + ch*64)*EV;
    const int rg = tid >> 5, q = tid & 31;
    float4 a1 = {0,0,0,0}, a2 = {0,0,0,0};
    #pragma unroll
    for (int i = 0; i < 8; ++i) {
        int r = i*8 + rg;
        fma4(a1, s_p1[r], p1[r*EV + q]);
        fma4(a2, s_p2[r], p2[r*EV + q]);
    }
    s_r1[tid] = a1; s_r2[tid] = a2;
    __syncthreads();
    for (int s = 128; s >= 32; s >>= 1) {
        if (tid < s) { add4(s_r1[tid], s_r1[tid+s]); add4(s_r2[tid], s_r2[tid+s]); }
        __syncthreads();
    }
    if (tid < 32) {
        float4 t1 = s_r1[tid], t2 = s_r2[tid];
        atomicAdd(&out[b*2*E_ + tid*4+0], t1.x);
        atomicAdd(&out[b*2*E_ + tid*4+1], t1.y);
        atomicAdd(&out[b*2*E_ + tid*4+2], t1.z);
        atomicAdd(&out[b*2*E_ + tid*4+3], t1.w);
        atomicAdd(&out[b*2*E_ + E_ + tid*4+0], t2.x);
        atomicAdd(&out[b*2*E_ + E_ + tid*4+1], t2.y);
        atomicAdd(&out[b*2*E_ + E_ + tid*4+2], t2.z);
        atomicAdd(&out[b*2*E_ + E_ + tid*4+3], t2.w);
    }
}

extern "C" void kernel_launch(void* const* d_in, const int* in_sizes, int n_in,
                              void* d_out, int out_size, void* d_ws, size_t ws_size,
                              hipStream_t stream) {
    const float* x1 = (const float*)d_in[0];
    const float* x2 = (const float*)d_in[1];
    const float* W1 = (const float*)d_in[2];
    const float* b1 = (const float*)d_in[3];
    const float* U1 = (const float*)d_in[4];
    const float* W2 = (const float*)d_in[5];
    const float* b2 = (const float*)d_in[6];
    const float* U2 = (const float*)d_in[7];
    float* ws  = (float*)d_ws;
    float* out = (float*)d_out;

    k0_zero<<<dim3((WS_ACC_N + OUT_N) / 256), 256, 0, stream>>>(ws, out);
    k1_sx<<<dim3(B_, 32), 256, 0, stream>>>(x1, x2, ws);
    k2_wc<<<dim3(B_, 32), 256, 0, stream>>>(x1, x2, W1, b1, W2, b2, ws);
    k3_et_softmax<<<dim3(B_, 2), 256, 0, stream>>>(U1, U2, ws);
    k5_out<<<dim3(B_, 32), 256, 0, stream>>>(x1, x2, ws, out);
}

// Round 5
// 148.947 us; speedup vs baseline: 1.0904x; 1.0415x over previous
//
#include <hip/hip_runtime.h>

// B=32, T=2048, E=128, fp32. S (B,T,T) never materialized:
//   sx1[b]=sum_t x1[b,t,:], sx2[b]=sum_t x2[b,t,:]
//   w1[t]=x1[b,t].sx2[b]; c1=(1/T) sum_t w1[t]*x2[b,t,:]   (sym. for c2)
//   et1[t]=c1.U1[:,t] + x1[b,t].W1 + b1[t]; softmax; o1=sum_t at1[t]*x1[b,t,:]
// 4 plain launches, no global atomics except final out accumulation.

#define B_ 32
#define T_ 2048
#define E_ 128
#define EV (E_/4)
#define INV_T (1.0f/2048.0f)

// ws float layout (all partial slots fully written before read -> no zeroing)
#define WS_PSX1 0                          // B*16*E  partial sx1
#define WS_PSX2 (B_*16*E_)                 // B*16*E  partial sx2
#define WS_PC1  (2*B_*16*E_)               // B*32*E  partial c1
#define WS_PC2  (2*B_*16*E_ + B_*32*E_)    // B*32*E  partial c2
#define WS_ET1  (2*B_*16*E_ + 2*B_*32*E_)  // B*T  (becomes probabilities)
#define WS_ET2  (WS_ET1 + B_*T_)           // B*T

__device__ __forceinline__ float dot4(float4 a, float4 b) {
    return a.x*b.x + a.y*b.y + a.z*b.z + a.w*b.w;
}
__device__ __forceinline__ void fma4(float4& a, float s, const float4 v) {
    a.x += s*v.x; a.y += s*v.y; a.z += s*v.z; a.w += s*v.w;
}
__device__ __forceinline__ void add4(float4& a, const float4 v) {
    a.x += v.x; a.y += v.y; a.z += v.z; a.w += v.w;
}

// ---------------- K1: partial column sums (128 rows/block, no atomics) ----------------
__global__ __launch_bounds__(256)
void k1_psx(const float* __restrict__ x1, const float* __restrict__ x2,
            float* __restrict__ ws) {
    __shared__ float4 s_r1[256], s_r2[256];
    const int b = blockIdx.x, g = blockIdx.y, tid = threadIdx.x;
    const float4* p1 = (const float4*)x1 + ((size_t)b*T_ + g*128)*EV;
    const float4* p2 = (const float4*)x2 + ((size_t)b*T_ + g*128)*EV;
    const int rg = tid >> 5, q = tid & 31;
    float4 a1 = {0,0,0,0}, a2 = {0,0,0,0};
    #pragma unroll
    for (int i = 0; i < 16; ++i) {
        int r = i*8 + rg;
        add4(a1, p1[r*EV + q]);
        add4(a2, p2[r*EV + q]);
    }
    s_r1[tid] = a1; s_r2[tid] = a2;
    __syncthreads();
    for (int s = 128; s >= 32; s >>= 1) {
        if (tid < s) { add4(s_r1[tid], s_r1[tid+s]); add4(s_r2[tid], s_r2[tid+s]); }
        __syncthreads();
    }
    if (tid < 32) {
        ((float4*)(ws + WS_PSX1))[(b*16 + g)*EV + tid] = s_r1[tid];
        ((float4*)(ws + WS_PSX2))[(b*16 + g)*EV + tid] = s_r2[tid];
    }
}

// ---------------- K2: reduce psx, row weights, x.W logits (et init), c partials ----------------
__global__ __launch_bounds__(256)
void k2_wc(const float* __restrict__ x1, const float* __restrict__ x2,
           const float* __restrict__ W1, const float* __restrict__ b1,
           const float* __restrict__ W2, const float* __restrict__ b2,
           float* __restrict__ ws) {
    __shared__ float4 s_r1[256], s_r2[256];
    __shared__ float  s_a[E_], s_b[E_], s_wa[E_], s_wb[E_];  // sx1,sx2,W1,W2
    __shared__ float  s_w1[64], s_w2[64];
    const int b = blockIdx.x, ch = blockIdx.y, tid = threadIdx.x;
    if (tid < E_) {
        float sa = 0.f, sb = 0.f;
        #pragma unroll
        for (int g = 0; g < 16; ++g) {
            sa += ws[WS_PSX1 + (b*16 + g)*E_ + tid];
            sb += ws[WS_PSX2 + (b*16 + g)*E_ + tid];
        }
        s_a[tid] = sa;
        s_b[tid] = sb;
        s_wa[tid] = W1[tid];
        s_wb[tid] = W2[tid];
    }
    __syncthreads();
    const float4* p1 = (const float4*)x1 + ((size_t)b*T_ + ch*64)*EV;
    const float4* p2 = (const float4*)x2 + ((size_t)b*T_ + ch*64)*EV;
    const float4* sx1v = (const float4*)s_a;
    const float4* sx2v = (const float4*)s_b;
    const float4* W1v  = (const float4*)s_wa;
    const float4* W2v  = (const float4*)s_wb;
    const int rowoff = tid >> 5, q = tid & 31;

    // tile loaded once into registers; reused by both phases
    float4 v1[8], v2[8];
    #pragma unroll
    for (int i = 0; i < 8; ++i) {
        int r = i*8 + rowoff;
        v1[i] = p1[r*EV + q];
        v2[i] = p2[r*EV + q];
    }

    float* et1 = ws + WS_ET1 + (size_t)b*T_ + ch*64;
    float* et2 = ws + WS_ET2 + (size_t)b*T_ + ch*64;
    #pragma unroll
    for (int i = 0; i < 8; ++i) {
        int r = i*8 + rowoff;
        float pw1 = dot4(v1[i], sx2v[q]);    // x1 . sx2
        float px1 = dot4(v1[i], W1v[q]);     // x1 . W1
        float pw2 = dot4(v2[i], sx1v[q]);    // x2 . sx1
        float px2 = dot4(v2[i], W2v[q]);     // x2 . W2
        #pragma unroll
        for (int m = 1; m <= 16; m <<= 1) {  // reduce within 32-lane half-wave
            pw1 += __shfl_xor(pw1, m);
            px1 += __shfl_xor(px1, m);
            pw2 += __shfl_xor(pw2, m);
            px2 += __shfl_xor(px2, m);
        }
        if (q == 0) {
            s_w1[r] = pw1; s_w2[r] = pw2;
            int trow = ch*64 + r;
            et1[r] = px1 + b1[trow];
            et2[r] = px2 + b2[trow];
        }
    }
    __syncthreads();

    float4 a1 = {0,0,0,0}, a2 = {0,0,0,0};
    #pragma unroll
    for (int i = 0; i < 8; ++i) {
        int r = i*8 + rowoff;
        fma4(a1, s_w1[r], v2[i]);
        fma4(a2, s_w2[r], v1[i]);
    }
    s_r1[tid] = a1; s_r2[tid] = a2;
    __syncthreads();
    for (int s = 128; s >= 32; s >>= 1) {
        if (tid < s) { add4(s_r1[tid], s_r1[tid+s]); add4(s_r2[tid], s_r2[tid+s]); }
        __syncthreads();
    }
    if (tid < 32) {
        float4 t1 = s_r1[tid], t2 = s_r2[tid];
        t1.x *= INV_T; t1.y *= INV_T; t1.z *= INV_T; t1.w *= INV_T;
        t2.x *= INV_T; t2.y *= INV_T; t2.z *= INV_T; t2.w *= INV_T;
        ((float4*)(ws + WS_PC1))[(b*32 + ch)*EV + tid] = t1;
        ((float4*)(ws + WS_PC2))[(b*32 + ch)*EV + tid] = t2;
    }
}

// ---------------- K3: reduce c, et += c.U, softmax -> probabilities; zero out ----------------
__global__ __launch_bounds__(512)
void k3_et_softmax(const float* __restrict__ U1, const float* __restrict__ U2,
                   float* __restrict__ ws, float* __restrict__ out) {
    __shared__ float s_c[E_];
    __shared__ float red[512];
    const int b = blockIdx.x, sel = blockIdx.y, tid = threadIdx.x;
    const float* U = sel ? U2 : U1;                       // (E, T) row-major
    const float* pc = ws + (sel ? WS_PC2 : WS_PC1);
    float4* et4 = (float4*)(ws + (sel ? WS_ET2 : WS_ET1) + (size_t)b*T_);
    if (tid < E_) {
        float s = 0.f;
        #pragma unroll
        for (int ch = 0; ch < 32; ++ch) s += pc[(b*32 + ch)*E_ + tid];
        s_c[tid] = s;
    } else if (tid >= 256 && tid < 256 + E_) {
        out[b*2*E_ + sel*E_ + (tid - 256)] = 0.f;         // zero out slice for K5
    }
    __syncthreads();
    const float4* U4 = (const float4*)U;                  // E x (T/4), T/4 = 512
    float4 acc = et4[tid];                                // et init (x.W + b)
    #pragma unroll 4
    for (int e = 0; e < E_; ++e) {
        fma4(acc, s_c[e], U4[(size_t)e*(T_/4) + tid]);
    }
    float m = fmaxf(fmaxf(acc.x, acc.y), fmaxf(acc.z, acc.w));
    red[tid] = m; __syncthreads();
    for (int s = 256; s > 0; s >>= 1) {
        if (tid < s) red[tid] = fmaxf(red[tid], red[tid+s]);
        __syncthreads();
    }
    m = red[0]; __syncthreads();
    float4 e4;
    e4.x = __expf(acc.x - m); e4.y = __expf(acc.y - m);
    e4.z = __expf(acc.z - m); e4.w = __expf(acc.w - m);
    red[tid] = e4.x + e4.y + e4.z + e4.w;
    __syncthreads();
    for (int s = 256; s > 0; s >>= 1) {
        if (tid < s) red[tid] += red[tid+s];
        __syncthreads();
    }
    float il = 1.f / red[0];
    e4.x *= il; e4.y *= il; e4.z *= il; e4.w *= il;
    et4[tid] = e4;                                        // et now holds at[t]
}

// ---------------- K5: o = sum_t at[t]*x[t,:] (128 rows/block) ----------------
__global__ __launch_bounds__(256)
void k5_out(const float* __restrict__ x1, const float* __restrict__ x2,
            const float* __restrict__ ws, float* __restrict__ out) {
    __shared__ float4 s_r1[256], s_r2[256];
    __shared__ float s_p1[128], s_p2[128];
    const int b = blockIdx.x, g = blockIdx.y, tid = threadIdx.x;
    const float* pr1 = ws + WS_ET1 + (size_t)b*T_ + g*128;
    const float* pr2 = ws + WS_ET2 + (size_t)b*T_ + g*128;
    if (tid < 128)  s_p1[tid] = pr1[tid];
    else            s_p2[tid - 128] = pr2[tid - 128];
    __syncthreads();
    const float4* p1 = (const float4*)x1 + ((size_t)b*T_ + g*128)*EV;
    const float4* p2 = (const float4*)x2 + ((size_t)b*T_ + g*128)*EV;
    const int rg = tid >> 5, q = tid & 31;
    float4 a1 = {0,0,0,0}, a2 = {0,0,0,0};
    #pragma unroll
    for (int i = 0; i < 16; ++i) {
        int r = i*8 + rg;
        fma4(a1, s_p1[r], p1[r*EV + q]);
        fma4(a2, s_p2[r], p2[r*EV + q]);
    }
    s_r1[tid] = a1; s_r2[tid] = a2;
    __syncthreads();
    for (int s = 128; s >= 32; s >>= 1) {
        if (tid < s) { add4(s_r1[tid], s_r1[tid+s]); add4(s_r2[tid], s_r2[tid+s]); }
        __syncthreads();
    }
    if (tid < 32) {
        float4 t1 = s_r1[tid], t2 = s_r2[tid];
        atomicAdd(&out[b*2*E_ + tid*4+0], t1.x);
        atomicAdd(&out[b*2*E_ + tid*4+1], t1.y);
        atomicAdd(&out[b*2*E_ + tid*4+2], t1.z);
        atomicAdd(&out[b*2*E_ + tid*4+3], t1.w);
        atomicAdd(&out[b*2*E_ + E_ + tid*4+0], t2.x);
        atomicAdd(&out[b*2*E_ + E_ + tid*4+1], t2.y);
        atomicAdd(&out[b*2*E_ + E_ + tid*4+2], t2.z);
        atomicAdd(&out[b*2*E_ + E_ + tid*4+3], t2.w);
    }
}

extern "C" void kernel_launch(void* const* d_in, const int* in_sizes, int n_in,
                              void* d_out, int out_size, void* d_ws, size_t ws_size,
                              hipStream_t stream) {
    const float* x1 = (const float*)d_in[0];
    const float* x2 = (const float*)d_in[1];
    const float* W1 = (const float*)d_in[2];
    const float* b1 = (const float*)d_in[3];
    const float* U1 = (const float*)d_in[4];
    const float* W2 = (const float*)d_in[5];
    const float* b2 = (const float*)d_in[6];
    const float* U2 = (const float*)d_in[7];
    float* ws  = (float*)d_ws;
    float* out = (float*)d_out;

    k1_psx<<<dim3(B_, 16), 256, 0, stream>>>(x1, x2, ws);
    k2_wc<<<dim3(B_, 32), 256, 0, stream>>>(x1, x2, W1, b1, W2, b2, ws);
    k3_et_softmax<<<dim3(B_, 2), 512, 0, stream>>>(U1, U2, ws, out);
    k5_out<<<dim3(B_, 16), 256, 0, stream>>>(x1, x2, ws, out);
}